// Round 3
// baseline (47.322 us; speedup 1.0000x reference)
//
#include <hip/hip_runtime.h>
#include <math.h>

#define GRID_RES 128
#define M_TOT (GRID_RES * GRID_RES)
#define N_PTS 4096
#define B_SZ 4
#define KSPLIT 32
#define KCH (N_PTS / KSPLIT)   // 128 K per block
#define KC 64                  // K per stage
#define WYP 68                 // padded row stride (words) for wy/yw: 4-row bank shift
// exp(-0.5*d^2/sigma^2), sigma=0.1 -> exp(-50*d^2) = exp2(-72.13475...*d^2)
#define NEG50_LOG2E -72.134752044448170f

// ---- Fused kernel: compute RBF weights on the fly, GEMM into K-partials ----
// grid: (KSPLIT, 2, B). Block tile: 64 gy x 128 gx, K-chunk 128 (2 stages of 64).
// 256 threads; per-thread micro-tile 4 gy x 8 gx x 2 channels.
__global__ __launch_bounds__(256) void fused_gemm(const float* __restrict__ x_c,
                                                  const float* __restrict__ y_c,
                                                  const int* __restrict__ mask,
                                                  const float* __restrict__ gp,
                                                  float* __restrict__ partial) {
    const int ks  = blockIdx.x;
    const int tyb = blockIdx.y;       // 0..1 : which 64-row gy tile
    const int b   = blockIdx.z;
    const int tid = threadIdx.x;
    const int txi = tid & 15;
    const int tyi = tid >> 4;         // 0..15
    const int gx0 = txi * 8;          // 8 gx columns per thread
    const int r0  = tyi * 4;          // 4 gy rows per thread
    const int gy0 = tyb * 64;
    const int n0  = ks * KCH;
    const size_t inoff = (size_t)b * N_PTS;

    __shared__ __align__(16) float cx[128];
    __shared__ __align__(16) float cy[64];
    __shared__ __align__(16) float pxs[64], pys[64], yvs[64], mks[64];
    __shared__ __align__(16) float wx_s[64][128];   // 32 KB
    __shared__ __align__(16) float wy_s[64][WYP];   // 17 KB
    __shared__ __align__(16) float yw_s[64][WYP];   // 17 KB

    // coordinates (once per block)
    if (tid < 128) cx[tid] = gp[tid];                               // grid_x row 0
    else if (tid < 192) cy[tid - 128] = gp[M_TOT + (gy0 + tid - 128) * GRID_RES];

    float accd[4][8], accw[4][8];
    #pragma unroll
    for (int i = 0; i < 4; ++i)
        #pragma unroll
        for (int j = 0; j < 8; ++j) { accd[i][j] = 0.f; accw[i][j] = 0.f; }

    for (int stage = 0; stage < KCH / KC; ++stage) {
        const int nb = n0 + stage * KC;
        __syncthreads();   // protect prev-stage LDS reads (and coord writes, stage 0)
        if (tid < 64) {
            const float2 xy = *(const float2*)&x_c[(inoff + nb + tid) * 2];
            pxs[tid] = xy.x;
            pys[tid] = xy.y;
            yvs[tid] = y_c[inoff + nb + tid];
            mks[tid] = (mask[inoff + nb + tid] != 0) ? 1.0f : 0.0f;
        }
        __syncthreads();
        // Wx tile: 64 rows x 128 gx. thread: fixed gx = tid&127, rows rbase..rbase+31
        {
            const int gx    = tid & 127;
            const int rbase = (tid >> 7) * 32;
            const float cxv = cx[gx];
            #pragma unroll 8
            for (int j = 0; j < 32; ++j) {
                const float d = pxs[rbase + j] - cxv;
                wx_s[rbase + j][gx] = exp2f(NEG50_LOG2E * d * d);
            }
        }
        // Wy / YWy tiles: 64 gy rows x 64 k. thread: fixed k = tid&63, 16 gy rows
        {
            const int k     = tid & 63;
            const int gbase = (tid >> 6) * 16;
            const float pyv = pys[k];
            const float yvv = yvs[k];
            const float mkv = mks[k];
            #pragma unroll 8
            for (int j = 0; j < 16; ++j) {
                const float d  = pyv - cy[gbase + j];
                const float wy = exp2f(NEG50_LOG2E * d * d) * mkv;
                wy_s[gbase + j][k] = wy;
                yw_s[gbase + j][k] = wy * yvv;
            }
        }
        __syncthreads();

        for (int nn = 0; nn < KC; nn += 4) {
            float4 wxa[4], wxb[4], wyv4[4], ywv4[4];
            #pragma unroll
            for (int j = 0; j < 4; ++j) {
                wxa[j] = *(const float4*)&wx_s[nn + j][gx0];
                wxb[j] = *(const float4*)&wx_s[nn + j][gx0 + 4];
            }
            #pragma unroll
            for (int i = 0; i < 4; ++i) wyv4[i] = *(const float4*)&wy_s[r0 + i][nn];
            #pragma unroll
            for (int i = 0; i < 4; ++i) ywv4[i] = *(const float4*)&yw_s[r0 + i][nn];
            #pragma unroll
            for (int i = 0; i < 4; ++i) {
                const float* wyp = (const float*)&wyv4[i];
                const float* ywp = (const float*)&ywv4[i];
                #pragma unroll
                for (int t = 0; t < 4; ++t) {
                    const float a = wyp[t];
                    const float c = ywp[t];
                    const float* wxpa = (const float*)&wxa[t];
                    const float* wxpb = (const float*)&wxb[t];
                    #pragma unroll
                    for (int j = 0; j < 4; ++j) {
                        accd[i][j]     = fmaf(a, wxpa[j], accd[i][j]);
                        accw[i][j]     = fmaf(c, wxpa[j], accw[i][j]);
                        accd[i][j + 4] = fmaf(a, wxpb[j], accd[i][j + 4]);
                        accw[i][j + 4] = fmaf(c, wxpb[j], accw[i][j + 4]);
                    }
                }
            }
        }
    }

    float* pd = partial + (((size_t)ks * B_SZ + b) * 2 + 0) * M_TOT;
    float* pw = partial + (((size_t)ks * B_SZ + b) * 2 + 1) * M_TOT;
    #pragma unroll
    for (int i = 0; i < 4; ++i) {
        const int row = gy0 + r0 + i;
        *(float4*)&pd[row * GRID_RES + gx0]     = make_float4(accd[i][0], accd[i][1], accd[i][2], accd[i][3]);
        *(float4*)&pd[row * GRID_RES + gx0 + 4] = make_float4(accd[i][4], accd[i][5], accd[i][6], accd[i][7]);
        *(float4*)&pw[row * GRID_RES + gx0]     = make_float4(accw[i][0], accw[i][1], accw[i][2], accw[i][3]);
        *(float4*)&pw[row * GRID_RES + gx0 + 4] = make_float4(accw[i][4], accw[i][5], accw[i][6], accw[i][7]);
    }
}

// ------------- Phase 2: reduce K-partials + normalize ------------------------
__global__ __launch_bounds__(256) void reduce_kernel(const float* __restrict__ partial,
                                                     float* __restrict__ out) {
    const int idx = blockIdx.x * 256 + threadIdx.x;   // 0 .. B*M-1
    const int b = idx >> 14;
    const int m = idx & (M_TOT - 1);
    float d = 0.f, w = 0.f;
    #pragma unroll
    for (int ks = 0; ks < KSPLIT; ++ks) {
        d += partial[(((size_t)ks * B_SZ + b) * 2 + 0) * M_TOT + m];
        w += partial[(((size_t)ks * B_SZ + b) * 2 + 1) * M_TOT + m];
    }
    out[((size_t)b * 2 + 0) * M_TOT + m] = d;
    out[((size_t)b * 2 + 1) * M_TOT + m] = w / (d + 1e-5f);
}

extern "C" void kernel_launch(void* const* d_in, const int* in_sizes, int n_in,
                              void* d_out, int out_size, void* d_ws, size_t ws_size,
                              hipStream_t stream) {
    const float* x_c  = (const float*)d_in[0];   // (B,N,2)
    const float* y_c  = (const float*)d_in[1];   // (B,N,1)
    const float* gp   = (const float*)d_in[2];   // (2,M)
    const int* mask   = (const int*)d_in[3];     // (B,N) bool -> int32
    float* out = (float*)d_out;                  // (B,2,128,128)

    float* partial = (float*)d_ws;               // KSPLIT*B*2*M floats = 16 MB

    fused_gemm<<<dim3(KSPLIT, 2, B_SZ), 256, 0, stream>>>(x_c, y_c, mask, gp, partial);
    reduce_kernel<<<B_SZ * M_TOT / 256, 256, 0, stream>>>(partial, out);
}

// Round 4
// 45.487 us; speedup vs baseline: 1.0404x; 1.0404x over previous
//
#include <hip/hip_runtime.h>
#include <math.h>

#define GRID_RES 128
#define M_TOT (GRID_RES * GRID_RES)
#define N_PTS 4096
#define B_SZ 4
#define KSPLIT 32
#define KCH (N_PTS / KSPLIT)   // 128 K per block
#define KC 64                  // K per stage (2 stages)
#define WYP 68                 // padded row stride for wy/yw
// exp(-0.5*d^2/sigma^2), sigma=0.1 -> exp(-50*d^2) = exp2(-72.1347...*d^2)
#define NEG50_LOG2E -72.134752044448170f

// ---- Fused kernel: compute RBF weights on the fly, GEMM into K-partials ----
// grid: (KSPLIT, 4, B) = 512 blocks. Tile: 32 gy x 128 gx, K-chunk 128.
// 256 threads; micro-tile 4 gy x 4 gx x 2 channels. 2 blocks/CU, 2 waves/SIMD.
__global__ __launch_bounds__(256, 2) void fused_gemm(const float* __restrict__ x_c,
                                                     const float* __restrict__ y_c,
                                                     const int* __restrict__ mask,
                                                     const float* __restrict__ gp,
                                                     float* __restrict__ partial) {
    const int ks  = blockIdx.x;
    const int tyb = blockIdx.y;       // 0..3 : which 32-row gy tile
    const int b   = blockIdx.z;
    const int tid = threadIdx.x;
    const int cg  = tid & 31;
    const int rg  = tid >> 5;         // 0..7
    const int c0  = cg * 4;           // 4 gx columns per thread
    const int r0  = rg * 4;           // 4 gy rows per thread
    const int gy0 = tyb * 32;
    const int n0  = ks * KCH;
    const size_t inoff = (size_t)b * N_PTS;

    __shared__ __align__(16) float cx[128];
    __shared__ __align__(16) float cy[32];
    __shared__ __align__(16) float pxs[KC], pys[KC], yvs[KC], mks[KC];
    __shared__ __align__(16) float wx_s[KC][128];   // 32 KB
    __shared__ __align__(16) float wy_s[32][WYP];   // 8.5 KB
    __shared__ __align__(16) float yw_s[32][WYP];   // 8.5 KB

    // coordinates (once per block)
    if (tid < 128) cx[tid] = gp[tid];                               // grid_x row 0
    else if (tid < 160) cy[tid - 128] = gp[M_TOT + (gy0 + tid - 128) * GRID_RES];

    float accd[4][4], accw[4][4];
    #pragma unroll
    for (int i = 0; i < 4; ++i)
        #pragma unroll
        for (int j = 0; j < 4; ++j) { accd[i][j] = 0.f; accw[i][j] = 0.f; }

    for (int stage = 0; stage < KCH / KC; ++stage) {
        const int nb = n0 + stage * KC;
        __syncthreads();   // protect prev-stage LDS reads (and coord writes, stage 0)
        if (tid < KC) {
            const float2 xy = *(const float2*)&x_c[(inoff + nb + tid) * 2];
            pxs[tid] = xy.x;
            pys[tid] = xy.y;
            yvs[tid] = y_c[inoff + nb + tid];
            mks[tid] = (mask[inoff + nb + tid] != 0) ? 1.0f : 0.0f;
        }
        __syncthreads();
        // Wx tile: KC rows x 128 gx. thread: fixed gx = tid&127, 32 rows
        {
            const int gx    = tid & 127;
            const int rbase = (tid >> 7) * 32;
            const float cxv = cx[gx];
            #pragma unroll 8
            for (int j = 0; j < 32; ++j) {
                const float d = pxs[rbase + j] - cxv;
                wx_s[rbase + j][gx] = exp2f(NEG50_LOG2E * d * d);
            }
        }
        // Wy / YWy tiles: 32 gy rows x KC k. thread: fixed k = tid&63, 8 gy rows
        {
            const int k     = tid & 63;
            const int gbase = (tid >> 6) * 8;
            const float pyv = pys[k];
            const float yvv = yvs[k];
            const float mkv = mks[k];
            #pragma unroll 8
            for (int j = 0; j < 8; ++j) {
                const float d  = pyv - cy[gbase + j];
                const float wy = exp2f(NEG50_LOG2E * d * d) * mkv;
                wy_s[gbase + j][k] = wy;
                yw_s[gbase + j][k] = wy * yvv;
            }
        }
        __syncthreads();

        #pragma unroll 4
        for (int nn = 0; nn < KC; nn += 4) {
            float4 wxv[4], wyv4[4], ywv4[4];
            #pragma unroll
            for (int j = 0; j < 4; ++j) wxv[j] = *(const float4*)&wx_s[nn + j][c0];
            #pragma unroll
            for (int i = 0; i < 4; ++i) wyv4[i] = *(const float4*)&wy_s[r0 + i][nn];
            #pragma unroll
            for (int i = 0; i < 4; ++i) ywv4[i] = *(const float4*)&yw_s[r0 + i][nn];
            #pragma unroll
            for (int i = 0; i < 4; ++i) {
                const float* wyp = (const float*)&wyv4[i];
                const float* ywp = (const float*)&ywv4[i];
                #pragma unroll
                for (int t = 0; t < 4; ++t) {
                    const float a = wyp[t];
                    const float c = ywp[t];
                    const float* wxp = (const float*)&wxv[t];
                    #pragma unroll
                    for (int j = 0; j < 4; ++j) {
                        accd[i][j] = fmaf(a, wxp[j], accd[i][j]);
                        accw[i][j] = fmaf(c, wxp[j], accw[i][j]);
                    }
                }
            }
        }
    }

    float* pd = partial + (((size_t)ks * B_SZ + b) * 2 + 0) * M_TOT;
    float* pw = partial + (((size_t)ks * B_SZ + b) * 2 + 1) * M_TOT;
    #pragma unroll
    for (int i = 0; i < 4; ++i) {
        const int row = gy0 + r0 + i;
        *(float4*)&pd[row * GRID_RES + c0] =
            make_float4(accd[i][0], accd[i][1], accd[i][2], accd[i][3]);
        *(float4*)&pw[row * GRID_RES + c0] =
            make_float4(accw[i][0], accw[i][1], accw[i][2], accw[i][3]);
    }
}

// ------------- Phase 2: reduce K-partials + normalize ------------------------
__global__ __launch_bounds__(256) void reduce_kernel(const float* __restrict__ partial,
                                                     float* __restrict__ out) {
    const int idx = blockIdx.x * 256 + threadIdx.x;   // 0 .. B*M-1
    const int b = idx >> 14;
    const int m = idx & (M_TOT - 1);
    float d = 0.f, w = 0.f;
    #pragma unroll
    for (int ks = 0; ks < KSPLIT; ++ks) {
        d += partial[(((size_t)ks * B_SZ + b) * 2 + 0) * M_TOT + m];
        w += partial[(((size_t)ks * B_SZ + b) * 2 + 1) * M_TOT + m];
    }
    out[((size_t)b * 2 + 0) * M_TOT + m] = d;
    out[((size_t)b * 2 + 1) * M_TOT + m] = w / (d + 1e-5f);
}

extern "C" void kernel_launch(void* const* d_in, const int* in_sizes, int n_in,
                              void* d_out, int out_size, void* d_ws, size_t ws_size,
                              hipStream_t stream) {
    const float* x_c  = (const float*)d_in[0];   // (B,N,2)
    const float* y_c  = (const float*)d_in[1];   // (B,N,1)
    const float* gp   = (const float*)d_in[2];   // (2,M)
    const int* mask   = (const int*)d_in[3];     // (B,N) bool -> int32
    float* out = (float*)d_out;                  // (B,2,128,128)

    float* partial = (float*)d_ws;               // KSPLIT*B*2*M floats = 16 MB

    fused_gemm<<<dim3(KSPLIT, 4, B_SZ), 256, 0, stream>>>(x_c, y_c, mask, gp, partial);
    reduce_kernel<<<B_SZ * M_TOT / 256, 256, 0, stream>>>(partial, out);
}

// Round 5
// 34.126 us; speedup vs baseline: 1.3867x; 1.3329x over previous
//
#include <hip/hip_runtime.h>
#include <hip/hip_bf16.h>
#include <math.h>

#define GRID_RES 128
#define M_TOT (GRID_RES * GRID_RES)
#define N_PTS 4096
#define B_SZ 4
#define KSPLIT 32
#define KCH 128            // K-chunk per block
#define APAD 136           // ushort row stride (128 + 8): 16B-aligned frags, optimal banks
// exp(-0.5*d^2/sigma^2), sigma=0.1 -> exp2(-72.1347...*d^2)
#define NEG50_LOG2E -72.134752044448170f

typedef __attribute__((ext_vector_type(8))) short short8;
typedef __attribute__((ext_vector_type(4))) float f32x4;

static __device__ __forceinline__ unsigned short f2bf(float f) {
    __hip_bfloat16 h = __float2bfloat16(f);   // RNE
    unsigned short u;
    __builtin_memcpy(&u, &h, 2);
    return u;
}

// ---- Fused MFMA kernel: generate bf16 weight tiles in LDS, MFMA-GEMM ----
// grid (KSPLIT, 2, B) = 256 blocks x 512 threads (8 waves, 2/SIMD).
// Block (ks, rt, b): A = (rt==0 ? Wy : Y*Wy) [128 gy x 128 k], Bt = WxT [128 gx x 128 k].
// Computes partial[ks][b][rt][gy][gx] = A x B over its K-chunk.
__global__ __launch_bounds__(512, 2) void mfma_gemm(const float* __restrict__ x_c,
                                                    const float* __restrict__ y_c,
                                                    const int* __restrict__ mask,
                                                    const float* __restrict__ gp,
                                                    float* __restrict__ partial) {
    const int ks = blockIdx.x;
    const int rt = blockIdx.y;       // 0: density (Wy), 1: weighted (Y*Wy)
    const int b  = blockIdx.z;
    const int t  = threadIdx.x;      // 0..511
    const int n0 = ks * KCH;
    const size_t inoff = (size_t)b * N_PTS;

    __shared__ __align__(16) unsigned short A_lds[128][APAD];    // [gy][k] bf16
    __shared__ __align__(16) unsigned short Bt_lds[128][APAD];   // [gx][k] bf16
    __shared__ float pxs[KCH], pys[KCH], scs[KCH];
    __shared__ float cxs[128], cys[128];

    // ---- stage inputs ----
    if (t < KCH) {
        const float2 xy = *(const float2*)&x_c[(inoff + n0 + t) * 2];
        pxs[t] = xy.x;
        pys[t] = xy.y;
        float sc = (mask[inoff + n0 + t] != 0) ? 1.0f : 0.0f;
        if (rt) sc *= y_c[inoff + n0 + t];
        scs[t] = sc;
    } else if (t < 256) {
        const int j = t - 128;
        cxs[j] = gp[j];                              // grid_x row 0
    } else if (t < 384) {
        const int j = t - 256;
        cys[j] = gp[M_TOT + j * GRID_RES];           // grid_y col 0
    }
    __syncthreads();

    // ---- generate bf16 tiles: thread t owns k-pair (2*k2, 2*k2+1), rows r0+8i ----
    {
        const int k2 = t & 63;
        const int r0 = t >> 6;
        const float pA0 = pys[2 * k2], pA1 = pys[2 * k2 + 1];
        const float sA0 = scs[2 * k2], sA1 = scs[2 * k2 + 1];
        const float pB0 = pxs[2 * k2], pB1 = pxs[2 * k2 + 1];
        #pragma unroll
        for (int i = 0; i < 16; ++i) {
            const int r = r0 + 8 * i;
            const float ca = cys[r];
            float d0 = pA0 - ca, d1 = pA1 - ca;
            const float a0 = exp2f(NEG50_LOG2E * d0 * d0) * sA0;
            const float a1 = exp2f(NEG50_LOG2E * d1 * d1) * sA1;
            *(unsigned int*)&A_lds[r][2 * k2] =
                (unsigned int)f2bf(a0) | ((unsigned int)f2bf(a1) << 16);
            const float cb = cxs[r];
            d0 = pB0 - cb; d1 = pB1 - cb;
            const float b0 = exp2f(NEG50_LOG2E * d0 * d0);
            const float b1 = exp2f(NEG50_LOG2E * d1 * d1);
            *(unsigned int*)&Bt_lds[r][2 * k2] =
                (unsigned int)f2bf(b0) | ((unsigned int)f2bf(b1) << 16);
        }
    }
    __syncthreads();

    // ---- MFMA phase: wave w -> rows (w&3)*32 (2 frags), cols (w>>2)*64 (4 frags) ----
    const int w  = t >> 6;
    const int l  = t & 63;
    const int lr = l & 15;           // fragment row/col index
    const int lg = l >> 4;           // k-group
    const int rbase = (w & 3) * 32;
    const int cbase = (w >> 2) * 64;

    f32x4 acc[2][4];
    #pragma unroll
    for (int rf = 0; rf < 2; ++rf)
        #pragma unroll
        for (int cf = 0; cf < 4; ++cf)
            acc[rf][cf] = (f32x4){0.f, 0.f, 0.f, 0.f};

    #pragma unroll
    for (int s = 0; s < 4; ++s) {
        const int koff = s * 32 + lg * 8;
        const short8 a0 = *(const short8*)&A_lds[rbase + lr][koff];
        const short8 a1 = *(const short8*)&A_lds[rbase + 16 + lr][koff];
        #pragma unroll
        for (int cf = 0; cf < 4; ++cf) {
            const short8 bv = *(const short8*)&Bt_lds[cbase + cf * 16 + lr][koff];
            acc[0][cf] = __builtin_amdgcn_mfma_f32_16x16x32_bf16(a0, bv, acc[0][cf], 0, 0, 0);
            acc[1][cf] = __builtin_amdgcn_mfma_f32_16x16x32_bf16(a1, bv, acc[1][cf], 0, 0, 0);
        }
    }

    // ---- write partial: C/D layout col=lane&15, row=(lane>>4)*4+reg ----
    float* pt = partial + (((size_t)ks * B_SZ + b) * 2 + rt) * M_TOT;
    #pragma unroll
    for (int rf = 0; rf < 2; ++rf)
        #pragma unroll
        for (int cf = 0; cf < 4; ++cf)
            #pragma unroll
            for (int r = 0; r < 4; ++r) {
                const int row = rbase + rf * 16 + lg * 4 + r;
                const int col = cbase + cf * 16 + lr;
                pt[row * GRID_RES + col] = acc[rf][cf][r];
            }
}

// ------------- Phase 2: reduce K-partials + normalize ------------------------
__global__ __launch_bounds__(256) void reduce_kernel(const float* __restrict__ partial,
                                                     float* __restrict__ out) {
    const int idx = blockIdx.x * 256 + threadIdx.x;   // 0 .. B*M-1
    const int b = idx >> 14;
    const int m = idx & (M_TOT - 1);
    float d = 0.f, w = 0.f;
    #pragma unroll
    for (int ks = 0; ks < KSPLIT; ++ks) {
        d += partial[(((size_t)ks * B_SZ + b) * 2 + 0) * M_TOT + m];
        w += partial[(((size_t)ks * B_SZ + b) * 2 + 1) * M_TOT + m];
    }
    out[((size_t)b * 2 + 0) * M_TOT + m] = d;
    out[((size_t)b * 2 + 1) * M_TOT + m] = w / (d + 1e-5f);
}

extern "C" void kernel_launch(void* const* d_in, const int* in_sizes, int n_in,
                              void* d_out, int out_size, void* d_ws, size_t ws_size,
                              hipStream_t stream) {
    const float* x_c  = (const float*)d_in[0];   // (B,N,2)
    const float* y_c  = (const float*)d_in[1];   // (B,N,1)
    const float* gp   = (const float*)d_in[2];   // (2,M)
    const int* mask   = (const int*)d_in[3];     // (B,N) bool -> int32
    float* out = (float*)d_out;                  // (B,2,128,128)

    float* partial = (float*)d_ws;               // KSPLIT*B*2*M floats = 16 MB

    mfma_gemm<<<dim3(KSPLIT, 2, B_SZ), 512, 0, stream>>>(x_c, y_c, mask, gp, partial);
    reduce_kernel<<<B_SZ * M_TOT / 256, 256, 0, stream>>>(partial, out);
}